// Round 9
// baseline (281.075 us; speedup 1.0000x reference)
//
#include <hip/hip_runtime.h>
#include <hip/hip_bf16.h>
#include <stdint.h>

#define SEQ    2048
#define DMODEL 4096
#define NH     32
#define NKVH   8
#define HDIM   128
#define KVD    (NKVH*HDIM)   // 1024
#define QD     (NH*HDIM)     // 4096
#define QKVN   (QD + 2*KVD)  // 6144 fused projection columns
#define ASCALE 0.08838834764831845f

typedef __attribute__((ext_vector_type(8))) short s8v;   // 8 bf16
typedef __attribute__((ext_vector_type(4))) short s4v;   // 4 bf16
typedef __attribute__((ext_vector_type(4))) float f4v;   // 4 f32

#define MFMA16(acc, a, b) \
  asm("v_mfma_f32_16x16x32_bf16 %0, %1, %2, %0" : "+v"(acc) : "v"(a), "v"(b))

#define SBAR() do { __builtin_amdgcn_sched_barrier(0); \
                    __builtin_amdgcn_s_barrier();      \
                    __builtin_amdgcn_sched_barrier(0); } while (0)

__device__ __forceinline__ void gl2lds16(const void* g, void* l) {
  __builtin_amdgcn_global_load_lds(
      (const __attribute__((address_space(1))) void*)g,
      (__attribute__((address_space(3))) void*)l, 16, 0, 0);
}

// ---------------- merged f32 -> bf16 convert (5 regions, one launch) ----------------
__global__ __launch_bounds__(256) void k_cvt5(const float* __restrict__ x,
                                              const float* __restrict__ wq,
                                              const float* __restrict__ wk,
                                              const float* __restrict__ wv,
                                              const float* __restrict__ wo,
                                              __hip_bfloat16* __restrict__ xb,
                                              __hip_bfloat16* __restrict__ wf,
                                              __hip_bfloat16* __restrict__ wob) {
  int i = blockIdx.x * 256 + threadIdx.x;
  const float* src;
  __hip_bfloat16* dst;
  float scale = 1.0f;
  if (i < 1048576)       { src = x;  dst = xb; }
  else if (i < 3145728)  { src = wq; dst = wf;  i -= 1048576; scale = ASCALE; }
  else if (i < 3670016)  { src = wk; dst = wf + (size_t)QD * DMODEL;  i -= 3145728; }
  else if (i < 4194304)  { src = wv; dst = wf + (size_t)(QD + KVD) * DMODEL; i -= 3670016; }
  else                   { src = wo; dst = wob; i -= 4194304; }
  const float4* p = (const float4*)src + (size_t)i * 2;
  float4 a = p[0], b = p[1];
  union { __hip_bfloat16 h[8]; s8v v; } o;
  o.h[0] = __float2bfloat16(a.x * scale); o.h[1] = __float2bfloat16(a.y * scale);
  o.h[2] = __float2bfloat16(a.z * scale); o.h[3] = __float2bfloat16(a.w * scale);
  o.h[4] = __float2bfloat16(b.x * scale); o.h[5] = __float2bfloat16(b.y * scale);
  o.h[6] = __float2bfloat16(b.z * scale); o.h[7] = __float2bfloat16(b.w * scale);
  *(s8v*)(dst + (size_t)i * 8) = o.v;
}

// ---------------- RoPE in-place on bf16 ----------------
__global__ __launch_bounds__(256) void k_rope(__hip_bfloat16* __restrict__ t,
                                              const float* __restrict__ fc,
                                              const float* __restrict__ fs, int heads) {
  int pid = blockIdx.x * 256 + threadIdx.x;
  int i = pid & 63;
  int rest = pid >> 6;
  int h = rest % heads;
  int s = rest / heads;
  size_t base = ((size_t)s * heads + h) * HDIM + 2 * i;
  uint32_t u = *(const uint32_t*)(t + base);
  __hip_bfloat16 hh[2]; *(uint32_t*)hh = u;
  float tr = __bfloat162float(hh[0]), ti = __bfloat162float(hh[1]);
  float c = fc[(size_t)s * 64 + i], sv = fs[(size_t)s * 64 + i];
  hh[0] = __float2bfloat16(tr * c - ti * sv);
  hh[1] = __float2bfloat16(tr * sv + ti * c);
  *(uint32_t*)(t + base) = *(uint32_t*)hh;
}

// ---------------- fused QKV projection: 2-phase read-ahead 256x192 ----------------
// All 22 fragment ds_reads issued at tile top; MFMA k0 overlaps in-flight k1 reads
// (compiler emits incremental lgkmcnt). lgkmcnt(0)+barrier, then stages of t+2
// (overwriting buf p) overlap MFMA k1. Boundary vmcnt(7) = one tile's stage group
// in flight. Accumulation order per element unchanged vs R6-R8 (bit-exact).
__global__ __launch_bounds__(512, 2) void k_qkv(const __hip_bfloat16* __restrict__ A,
                                                const __hip_bfloat16* __restrict__ W,
                                                __hip_bfloat16* __restrict__ Qb,
                                                __hip_bfloat16* __restrict__ Kc,
                                                __hip_bfloat16* __restrict__ Vt) {
  __shared__ __align__(16) __hip_bfloat16 sm[2][256 * 64 + 192 * 64];
  const int t5 = threadIdx.x;
  const int wave = t5 >> 6, lane = t5 & 63;
  const int lrow = lane & 15, kq = lane >> 4;
  const int wm = wave >> 2, wn = wave & 3;
  const int mt = blockIdx.x & 7, nt = blockIdx.x >> 3;
  const int m0 = mt * 256, n0 = nt * 192;

  auto stageA = [&](int p, int kt) {
#pragma unroll
    for (int it = 0; it < 4; ++it) {
      int chunk = it * 512 + t5;
      int r = chunk >> 3, cc = ((chunk & 7) ^ (r & 7)) * 8;
      gl2lds16(A + (size_t)(m0 + r) * DMODEL + kt * 64 + cc,
               (char*)&sm[p][0] + it * 8192 + wave * 1024);
    }
  };
  auto stageB = [&](int p, int kt) {
#pragma unroll
    for (int it = 0; it < 3; ++it) {
      int chunk = it * 512 + t5;
      int r = chunk >> 3, cc = ((chunk & 7) ^ (r & 7)) * 8;
      gl2lds16(W + (size_t)(n0 + r) * DMODEL + kt * 64 + cc,
               (char*)&sm[p][0] + 32768 + it * 8192 + wave * 1024);
    }
  };

  f4v acc[8][3] = {};

  stageA(0, 0); stageB(0, 0);
  stageA(1, 1); stageB(1, 1);

  const int NT = DMODEL / 64;
#pragma unroll 2
  for (int t = 0; t < NT; ++t) {
    const int p = t & 1;
    const __hip_bfloat16* As = &sm[p][0];
    const __hip_bfloat16* Bs = &sm[p][256 * 64];

    // tile boundary: tile t landed; tile t+1's 7 stage-loads stay in flight
    __builtin_amdgcn_sched_barrier(0);
    if (t == NT - 1) asm volatile("s_waitcnt vmcnt(0)" ::: "memory");
    else             asm volatile("s_waitcnt vmcnt(7)" ::: "memory");
    __builtin_amdgcn_s_barrier();
    __builtin_amdgcn_sched_barrier(0);

    // issue ALL fragment reads (22 b128) up front
    s8v a0[8], b0[3], a1[8], b1[3];
#pragma unroll
    for (int m = 0; m < 8; ++m) {
      int row = wm * 128 + m * 16 + lrow;
      a0[m] = *(const s8v*)&As[row * 64 + ((kq * 8) ^ ((row & 7) << 3))];
    }
#pragma unroll
    for (int n = 0; n < 3; ++n) {
      int row = wn * 48 + n * 16 + lrow;
      b0[n] = *(const s8v*)&Bs[row * 64 + ((kq * 8) ^ ((row & 7) << 3))];
    }
#pragma unroll
    for (int m = 0; m < 8; ++m) {
      int row = wm * 128 + m * 16 + lrow;
      a1[m] = *(const s8v*)&As[row * 64 + ((32 + kq * 8) ^ ((row & 7) << 3))];
    }
#pragma unroll
    for (int n = 0; n < 3; ++n) {
      int row = wn * 48 + n * 16 + lrow;
      b1[n] = *(const s8v*)&Bs[row * 64 + ((32 + kq * 8) ^ ((row & 7) << 3))];
    }

    // ph1: MFMA k0 (24) overlaps the in-flight k1 reads
    __builtin_amdgcn_s_setprio(1);
#pragma unroll
    for (int m = 0; m < 8; ++m)
#pragma unroll
      for (int n = 0; n < 3; ++n) MFMA16(acc[m][n], a0[m], b0[n]);
    __builtin_amdgcn_s_setprio(0);
    asm volatile("s_waitcnt lgkmcnt(0)" ::: "memory");  // all buf-p reads done
    SBAR();

    // ph2: stage tile t+2 into buf p (safe post-barrier), MFMA k1 (24)
    if (t + 2 < NT) { stageA(p, t + 2); stageB(p, t + 2); }
    __builtin_amdgcn_s_setprio(1);
#pragma unroll
    for (int m = 0; m < 8; ++m)
#pragma unroll
      for (int n = 0; n < 3; ++n) MFMA16(acc[m][n], a1[m], b1[n]);
    __builtin_amdgcn_s_setprio(0);
  }

#pragma unroll
  for (int m = 0; m < 8; ++m)
#pragma unroll
    for (int n = 0; n < 3; ++n) {
      int c = n0 + wn * 48 + n * 16 + lrow;
      int r0 = m0 + wm * 128 + m * 16 + kq * 4;
      if (c < QD) {
#pragma unroll
        for (int j = 0; j < 4; ++j)
          Qb[(size_t)(r0 + j) * QD + c] = __float2bfloat16(acc[m][n][j]);
      } else if (c < QD + KVD) {
#pragma unroll
        for (int j = 0; j < 4; ++j)
          Kc[(size_t)(r0 + j) * KVD + (c - QD)] = __float2bfloat16(acc[m][n][j]);
      } else {
        union { __hip_bfloat16 b[4]; s4v v; } u;
#pragma unroll
        for (int j = 0; j < 4; ++j) u.b[j] = __float2bfloat16(acc[m][n][j]);
        *(s4v*)&Vt[(size_t)(c - QD - KVD) * SEQ + r0] = u.v;
      }
    }
}

// ---------------- O-projection: 2-phase read-ahead 128x256 ----------------
__global__ __launch_bounds__(512, 2) void k_oproj(const __hip_bfloat16* __restrict__ A,
                                                  const __hip_bfloat16* __restrict__ B,
                                                  float* __restrict__ C) {
  __shared__ __align__(16) __hip_bfloat16 sm[2][128 * 64 + 256 * 64];
  const int t5 = threadIdx.x;
  const int wave = t5 >> 6, lane = t5 & 63;
  const int lrow = lane & 15, kq = lane >> 4;
  const int wm = wave >> 2, wn = wave & 3;
  const int m0 = blockIdx.y * 128, n0 = blockIdx.x * 256;

  auto stageA = [&](int p, int kt) {
#pragma unroll
    for (int it = 0; it < 2; ++it) {
      int chunk = it * 512 + t5;
      int r = chunk >> 3, cc = ((chunk & 7) ^ (r & 7)) * 8;
      gl2lds16(A + (size_t)(m0 + r) * QD + kt * 64 + cc,
               (char*)&sm[p][0] + it * 8192 + wave * 1024);
    }
  };
  auto stageB = [&](int p, int kt) {
#pragma unroll
    for (int it = 0; it < 4; ++it) {
      int chunk = it * 512 + t5;
      int r = chunk >> 3, cc = ((chunk & 7) ^ (r & 7)) * 8;
      gl2lds16(B + (size_t)(n0 + r) * QD + kt * 64 + cc,
               (char*)&sm[p][0] + 16384 + it * 8192 + wave * 1024);
    }
  };

  f4v acc[4][4] = {};

  stageA(0, 0); stageB(0, 0);
  stageA(1, 1); stageB(1, 1);

  const int NT = QD / 64;
#pragma unroll 2
  for (int t = 0; t < NT; ++t) {
    const int p = t & 1;
    const __hip_bfloat16* As = &sm[p][0];
    const __hip_bfloat16* Bs = &sm[p][128 * 64];

    __builtin_amdgcn_sched_barrier(0);
    if (t == NT - 1) asm volatile("s_waitcnt vmcnt(0)" ::: "memory");
    else             asm volatile("s_waitcnt vmcnt(6)" ::: "memory");
    __builtin_amdgcn_s_barrier();
    __builtin_amdgcn_sched_barrier(0);

    // issue ALL fragment reads (16 b128)
    s8v a0[4], b0[4], a1[4], b1[4];
#pragma unroll
    for (int m = 0; m < 4; ++m) {
      int row = wm * 64 + m * 16 + lrow;
      a0[m] = *(const s8v*)&As[row * 64 + ((kq * 8) ^ ((row & 7) << 3))];
    }
#pragma unroll
    for (int n = 0; n < 4; ++n) {
      int row = wn * 64 + n * 16 + lrow;
      b0[n] = *(const s8v*)&Bs[row * 64 + ((kq * 8) ^ ((row & 7) << 3))];
    }
#pragma unroll
    for (int m = 0; m < 4; ++m) {
      int row = wm * 64 + m * 16 + lrow;
      a1[m] = *(const s8v*)&As[row * 64 + ((32 + kq * 8) ^ ((row & 7) << 3))];
    }
#pragma unroll
    for (int n = 0; n < 4; ++n) {
      int row = wn * 64 + n * 16 + lrow;
      b1[n] = *(const s8v*)&Bs[row * 64 + ((32 + kq * 8) ^ ((row & 7) << 3))];
    }

    // ph1: MFMA k0 (16) overlaps in-flight k1 reads
    __builtin_amdgcn_s_setprio(1);
#pragma unroll
    for (int m = 0; m < 4; ++m)
#pragma unroll
      for (int n = 0; n < 4; ++n) MFMA16(acc[m][n], a0[m], b0[n]);
    __builtin_amdgcn_s_setprio(0);
    asm volatile("s_waitcnt lgkmcnt(0)" ::: "memory");
    SBAR();

    // ph2: stage tile t+2, MFMA k1 (16)
    if (t + 2 < NT) { stageA(p, t + 2); stageB(p, t + 2); }
    __builtin_amdgcn_s_setprio(1);
#pragma unroll
    for (int m = 0; m < 4; ++m)
#pragma unroll
      for (int n = 0; n < 4; ++n) MFMA16(acc[m][n], a1[m], b1[n]);
    __builtin_amdgcn_s_setprio(0);
  }

#pragma unroll
  for (int m = 0; m < 4; ++m)
#pragma unroll
    for (int n = 0; n < 4; ++n)
#pragma unroll
      for (int j = 0; j < 4; ++j) {
        int r = m0 + wm * 64 + m * 16 + kq * 4 + j;
        int c = n0 + wn * 64 + n * 16 + lrow;
        C[(size_t)r * DMODEL + c] = acc[m][n][j];
      }
}

// ---------------- causal flash attention: swapped-QK^T in-lane softmax (R8, verified) ----------------
__global__ __launch_bounds__(256, 2) void k_flash(const __hip_bfloat16* __restrict__ Q,
                                                  const __hip_bfloat16* __restrict__ Kb,
                                                  const __hip_bfloat16* __restrict__ Vtg,
                                                  __hip_bfloat16* __restrict__ O) {
  __shared__ __align__(16) __hip_bfloat16 Ks[2][64 * 128];
  __shared__ __align__(16) __hip_bfloat16 Vs[144 * 64];   // rows 128..143 = ones
  __shared__ __align__(16) __hip_bfloat16 Ps[4][16 * 64];
  const int qp = blockIdx.x, h = blockIdx.y, g = h >> 2;
  const int t = threadIdx.x, wave = t >> 6, lane = t & 63;
  const int lrow = lane & 15, kq = lane >> 4;
  const int qtA = qp, qtB = 31 - qp;

  s8v qfA[4], qfB[4];
  {
    const int qrA = qtA * 64 + wave * 16 + lrow;
    const int qrB = qtB * 64 + wave * 16 + lrow;
#pragma unroll
    for (int tt = 0; tt < 4; ++tt) {
      qfA[tt] = *(const s8v*)(Q + (size_t)qrA * QD + h * HDIM + tt * 32 + kq * 8);
      qfB[tt] = *(const s8v*)(Q + (size_t)qrB * QD + h * HDIM + tt * 32 + kq * 8);
    }
  }

  if (t < 128) {
    union { __hip_bfloat16 h8[8]; s8v v; } one;
#pragma unroll
    for (int e = 0; e < 8; ++e) one.h8[e] = __float2bfloat16(1.0f);
    *(s8v*)&Vs[128 * 64 + t * 8] = one.v;
  }

  f4v oA[9] = {}, oB[9] = {};   // [8] = l accumulator (ones-column)
  float mA = -1e30f, mB = -1e30f;

  auto stage_k = [&](int buf, int kv) {
#pragma unroll
    for (int it = 0; it < 4; ++it) {
      int chunk = it * 256 + t;
      int r = chunk >> 4, cc = ((chunk & 15) ^ (r & 7)) * 8;
      gl2lds16(Kb + (size_t)(kv * 64 + r) * KVD + g * HDIM + cc,
               (char*)&Ks[buf][0] + it * 4096 + wave * 1024);
    }
  };
  auto stage_v = [&](int kv) {
#pragma unroll
    for (int it = 0; it < 4; ++it) {
      int chunk = it * 256 + t;
      int d = chunk >> 3, cc = ((chunk & 7) ^ (d & 7)) * 8;
      gl2lds16(Vtg + (size_t)(g * HDIM + d) * SEQ + kv * 64 + cc,
               (char*)Vs + it * 4096 + wave * 1024);
    }
  };

  auto soft_pv = [&](f4v (&s)[4], int qt, int kv, f4v (&acc_o)[9], float& mrun) {
    __hip_bfloat16* P = &Ps[wave][0];
    const bool diag = (kv == qt);
    const int qi = qt * 64 + wave * 16 + lrow;
    const int swz = (lrow & 7) << 3;
    float pv[4][4];
    float mx = -1e30f;
#pragma unroll
    for (int n = 0; n < 4; ++n)
#pragma unroll
      for (int j = 0; j < 4; ++j) {
        float v = s[n][j];
        if (diag) {
          int ki = kv * 64 + n * 16 + kq * 4 + j;
          if (ki > qi) v = -1e30f;
        }
        pv[n][j] = v;
        mx = fmaxf(mx, v);
      }
    mx = fmaxf(mx, __shfl_xor(mx, 16, 64));
    mx = fmaxf(mx, __shfl_xor(mx, 32, 64));
    if (!__all(mx <= mrun)) {
      float mnew = fmaxf(mrun, mx);
      float fsc = __expf(mrun - mnew);
      mrun = mnew;
      float fj[4];
#pragma unroll
      for (int j = 0; j < 4; ++j) fj[j] = __shfl(fsc, kq * 4 + j, 64);
#pragma unroll
      for (int n = 0; n < 9; ++n) {
        acc_o[n][0] *= fj[0]; acc_o[n][1] *= fj[1];
        acc_o[n][2] *= fj[2]; acc_o[n][3] *= fj[3];
      }
    }
    asm volatile("" ::: "memory");
#pragma unroll
    for (int n = 0; n < 4; ++n) {
      union { __hip_bfloat16 b[4]; s4v v; } u;
#pragma unroll
      for (int j = 0; j < 4; ++j) u.b[j] = __float2bfloat16(__expf(pv[n][j] - mrun));
      *(s4v*)&P[lrow * 64 + ((n * 16 + kq * 4) ^ swz)] = u.v;
    }
    asm volatile("" ::: "memory");
#pragma unroll
    for (int tt = 0; tt < 2; ++tt) {
      s8v pa = *(const s8v*)&P[lrow * 64 + ((tt * 32 + kq * 8) ^ swz)];
#pragma unroll
      for (int n = 0; n < 9; ++n) {
        int d = n * 16 + lrow;
        s8v vf = *(const s8v*)&Vs[d * 64 + ((tt * 32 + kq * 8) ^ ((d & 7) << 3))];
        MFMA16(acc_o[n], pa, vf);
      }
    }
  };

  stage_k(0, 0);
  int cur = 0;
  for (int kv = 0; kv <= qtB; ++kv) {
    const bool actA = (kv <= qtA);
    __syncthreads();
    if (kv < qtB) stage_k(cur ^ 1, kv + 1);
    stage_v(kv);

    f4v sB[4] = {}, sA[4] = {};
    if (actA) {
#pragma unroll
      for (int tt = 0; tt < 4; ++tt)
#pragma unroll
        for (int n = 0; n < 4; ++n) {
          int row = n * 16 + lrow;
          s8v kf = *(const s8v*)&Ks[cur][row * 128 + ((tt * 32 + kq * 8) ^ ((row & 7) << 3))];
          MFMA16(sB[n], kf, qfB[tt]);
          MFMA16(sA[n], kf, qfA[tt]);
        }
    } else {
#pragma unroll
      for (int tt = 0; tt < 4; ++tt)
#pragma unroll
        for (int n = 0; n < 4; ++n) {
          int row = n * 16 + lrow;
          s8v kf = *(const s8v*)&Ks[cur][row * 128 + ((tt * 32 + kq * 8) ^ ((row & 7) << 3))];
          MFMA16(sB[n], kf, qfB[tt]);
        }
    }
    __syncthreads();

    soft_pv(sB, qtB, kv, oB, mB);
    if (actA) soft_pv(sA, qtA, kv, oA, mA);
    cur ^= 1;
  }

#pragma unroll
  for (int n = 0; n < 8; ++n)
#pragma unroll
    for (int j = 0; j < 4; ++j) {
      int d = n * 16 + lrow;
      int qiB = qtB * 64 + wave * 16 + kq * 4 + j;
      O[(size_t)qiB * QD + h * HDIM + d] = __float2bfloat16(oB[n][j] / oB[8][j]);
      int qiA = qtA * 64 + wave * 16 + kq * 4 + j;
      O[(size_t)qiA * QD + h * HDIM + d] = __float2bfloat16(oA[n][j] / oA[8][j]);
    }
}

// ---------------- launch ----------------
extern "C" void kernel_launch(void* const* d_in, const int* in_sizes, int n_in,
                              void* d_out, int out_size, void* d_ws, size_t ws_size,
                              hipStream_t stream) {
  const float* x  = (const float*)d_in[0];
  const float* fc = (const float*)d_in[1];
  const float* fs = (const float*)d_in[2];
  const float* wq = (const float*)d_in[3];
  const float* wk = (const float*)d_in[4];
  const float* wv = (const float*)d_in[5];
  const float* wo = (const float*)d_in[6];
  float* out = (float*)d_out;

  char* ws = (char*)d_ws;
  auto alloc = [&](size_t bytes) {
    char* p = ws;
    ws += (bytes + 255) & ~(size_t)255;
    return p;
  };
  __hip_bfloat16* xb  = (__hip_bfloat16*)alloc((size_t)SEQ * DMODEL * 2);
  __hip_bfloat16* wf  = (__hip_bfloat16*)alloc((size_t)QKVN * DMODEL * 2);
  __hip_bfloat16* wob = (__hip_bfloat16*)alloc((size_t)DMODEL * QD * 2);
  __hip_bfloat16* Qb  = (__hip_bfloat16*)alloc((size_t)SEQ * QD * 2);
  __hip_bfloat16* Kc  = (__hip_bfloat16*)alloc((size_t)SEQ * KVD * 2);
  __hip_bfloat16* Vtg = (__hip_bfloat16*)alloc((size_t)KVD * SEQ * 2);
  __hip_bfloat16* Ob  = (__hip_bfloat16*)alloc((size_t)SEQ * QD * 2);

  k_cvt5<<<dim3(24576), dim3(256), 0, stream>>>(x, wq, wk, wv, wo, xb, wf, wob);

  k_qkv<<<dim3(256), dim3(512), 0, stream>>>(xb, wf, Qb, Kc, Vtg);

  k_rope<<<dim3(SEQ * NH * 64 / 256), 256, 0, stream>>>(Qb, fc, fs, NH);
  k_rope<<<dim3(SEQ * NKVH * 64 / 256), 256, 0, stream>>>(Kc, fc, fs, NKVH);

  k_flash<<<dim3(16, NH), 256, 0, stream>>>(Qb, Kc, Vtg, Ob);

  k_oproj<<<dim3(DMODEL / 256, SEQ / 128), dim3(512), 0, stream>>>(Ob, wob, out);
}

// Round 10
// 280.513 us; speedup vs baseline: 1.0020x; 1.0020x over previous
//
#include <hip/hip_runtime.h>
#include <hip/hip_bf16.h>
#include <stdint.h>

#define SEQ    2048
#define DMODEL 4096
#define NH     32
#define NKVH   8
#define HDIM   128
#define KVD    (NKVH*HDIM)   // 1024
#define QD     (NH*HDIM)     // 4096
#define QKVN   (QD + 2*KVD)  // 6144 fused projection columns
#define ASCALE 0.08838834764831845f

typedef __attribute__((ext_vector_type(8))) short s8v;   // 8 bf16
typedef __attribute__((ext_vector_type(4))) short s4v;   // 4 bf16
typedef __attribute__((ext_vector_type(4))) float f4v;   // 4 f32

#define MFMA16(acc, a, b) \
  asm("v_mfma_f32_16x16x32_bf16 %0, %1, %2, %0" : "+v"(acc) : "v"(a), "v"(b))

#define SBAR() do { __builtin_amdgcn_sched_barrier(0); \
                    __builtin_amdgcn_s_barrier();      \
                    __builtin_amdgcn_sched_barrier(0); } while (0)

__device__ __forceinline__ void gl2lds16(const void* g, void* l) {
  __builtin_amdgcn_global_load_lds(
      (const __attribute__((address_space(1))) void*)g,
      (__attribute__((address_space(3))) void*)l, 16, 0, 0);
}

// ---------------- merged f32 -> bf16 convert (5 regions, one launch) ----------------
__global__ __launch_bounds__(256) void k_cvt5(const float* __restrict__ x,
                                              const float* __restrict__ wq,
                                              const float* __restrict__ wk,
                                              const float* __restrict__ wv,
                                              const float* __restrict__ wo,
                                              __hip_bfloat16* __restrict__ xb,
                                              __hip_bfloat16* __restrict__ wf,
                                              __hip_bfloat16* __restrict__ wob) {
  int i = blockIdx.x * 256 + threadIdx.x;
  const float* src;
  __hip_bfloat16* dst;
  float scale = 1.0f;
  if (i < 1048576)       { src = x;  dst = xb; }
  else if (i < 3145728)  { src = wq; dst = wf;  i -= 1048576; scale = ASCALE; }
  else if (i < 3670016)  { src = wk; dst = wf + (size_t)QD * DMODEL;  i -= 3145728; }
  else if (i < 4194304)  { src = wv; dst = wf + (size_t)(QD + KVD) * DMODEL; i -= 3670016; }
  else                   { src = wo; dst = wob; i -= 4194304; }
  const float4* p = (const float4*)src + (size_t)i * 2;
  float4 a = p[0], b = p[1];
  union { __hip_bfloat16 h[8]; s8v v; } o;
  o.h[0] = __float2bfloat16(a.x * scale); o.h[1] = __float2bfloat16(a.y * scale);
  o.h[2] = __float2bfloat16(a.z * scale); o.h[3] = __float2bfloat16(a.w * scale);
  o.h[4] = __float2bfloat16(b.x * scale); o.h[5] = __float2bfloat16(b.y * scale);
  o.h[6] = __float2bfloat16(b.z * scale); o.h[7] = __float2bfloat16(b.w * scale);
  *(s8v*)(dst + (size_t)i * 8) = o.v;
}

// ---------------- RoPE in-place on bf16 ----------------
__global__ __launch_bounds__(256) void k_rope(__hip_bfloat16* __restrict__ t,
                                              const float* __restrict__ fc,
                                              const float* __restrict__ fs, int heads) {
  int pid = blockIdx.x * 256 + threadIdx.x;
  int i = pid & 63;
  int rest = pid >> 6;
  int h = rest % heads;
  int s = rest / heads;
  size_t base = ((size_t)s * heads + h) * HDIM + 2 * i;
  uint32_t u = *(const uint32_t*)(t + base);
  __hip_bfloat16 hh[2]; *(uint32_t*)hh = u;
  float tr = __bfloat162float(hh[0]), ti = __bfloat162float(hh[1]);
  float c = fc[(size_t)s * 64 + i], sv = fs[(size_t)s * 64 + i];
  hh[0] = __float2bfloat16(tr * c - ti * sv);
  hh[1] = __float2bfloat16(tr * sv + ti * c);
  *(uint32_t*)(t + base) = *(uint32_t*)hh;
}

// ---------------- fused QKV projection: R8 4-phase, waves remapped 4M x 2N ----------------
// Wave-tile 64x96 (4x6 16x16 frags): reads/tile 20 vs 22 (LDS-read-bound kernel).
// Per-output K-accumulation order unchanged (bit-exact vs R8).
__global__ __launch_bounds__(512, 2) void k_qkv(const __hip_bfloat16* __restrict__ A,
                                                const __hip_bfloat16* __restrict__ W,
                                                __hip_bfloat16* __restrict__ Qb,
                                                __hip_bfloat16* __restrict__ Kc,
                                                __hip_bfloat16* __restrict__ Vt) {
  __shared__ __align__(16) __hip_bfloat16 sm[2][256 * 64 + 192 * 64];
  const int t5 = threadIdx.x;
  const int wave = t5 >> 6, lane = t5 & 63;
  const int lrow = lane & 15, kq = lane >> 4;
  const int wm = wave >> 1, wn = wave & 1;          // 4M x 2N
  const int mt = blockIdx.x & 7, nt = blockIdx.x >> 3;
  const int m0 = mt * 256, n0 = nt * 192;

  auto stageA = [&](int p, int kt) {
#pragma unroll
    for (int it = 0; it < 4; ++it) {
      int chunk = it * 512 + t5;
      int r = chunk >> 3, cc = ((chunk & 7) ^ (r & 7)) * 8;
      gl2lds16(A + (size_t)(m0 + r) * DMODEL + kt * 64 + cc,
               (char*)&sm[p][0] + it * 8192 + wave * 1024);
    }
  };
  auto stageB = [&](int p, int kt) {
#pragma unroll
    for (int it = 0; it < 3; ++it) {
      int chunk = it * 512 + t5;
      int r = chunk >> 3, cc = ((chunk & 7) ^ (r & 7)) * 8;
      gl2lds16(W + (size_t)(n0 + r) * DMODEL + kt * 64 + cc,
               (char*)&sm[p][0] + 32768 + it * 8192 + wave * 1024);
    }
  };

  f4v acc[4][6] = {};

  stageA(0, 0); stageB(0, 0);
  stageA(1, 1); stageB(1, 1);

  const int NT = DMODEL / 64;
#pragma unroll 2
  for (int t = 0; t < NT; ++t) {
    const int p = t & 1;
    const __hip_bfloat16* As = &sm[p][0];
    const __hip_bfloat16* Bs = &sm[p][256 * 64];

    // boundary: tile t landed; tile t+1's 7 stage-loads stay in flight
    __builtin_amdgcn_sched_barrier(0);
    if (t == NT - 1) asm volatile("s_waitcnt vmcnt(0)" ::: "memory");
    else             asm volatile("s_waitcnt vmcnt(7)" ::: "memory");
    __builtin_amdgcn_s_barrier();
    __builtin_amdgcn_sched_barrier(0);

    // ph1: read k0 frags (10), MFMA k0 x m0-1 (12)
    s8v a0[4], b0[6];
#pragma unroll
    for (int m = 0; m < 4; ++m) {
      int row = wm * 64 + m * 16 + lrow;
      a0[m] = *(const s8v*)&As[row * 64 + ((kq * 8) ^ ((row & 7) << 3))];
    }
#pragma unroll
    for (int n = 0; n < 6; ++n) {
      int row = wn * 96 + n * 16 + lrow;
      b0[n] = *(const s8v*)&Bs[row * 64 + ((kq * 8) ^ ((row & 7) << 3))];
    }
    __builtin_amdgcn_s_setprio(1);
#pragma unroll
    for (int m = 0; m < 2; ++m)
#pragma unroll
      for (int n = 0; n < 6; ++n) MFMA16(acc[m][n], a0[m], b0[n]);
    __builtin_amdgcn_s_setprio(0);
    SBAR();

    // ph2: read k1 frags (10), MFMA k0 x m2-3 (12)
    s8v a1[4], b1[6];
#pragma unroll
    for (int m = 0; m < 4; ++m) {
      int row = wm * 64 + m * 16 + lrow;
      a1[m] = *(const s8v*)&As[row * 64 + ((32 + kq * 8) ^ ((row & 7) << 3))];
    }
#pragma unroll
    for (int n = 0; n < 6; ++n) {
      int row = wn * 96 + n * 16 + lrow;
      b1[n] = *(const s8v*)&Bs[row * 64 + ((32 + kq * 8) ^ ((row & 7) << 3))];
    }
    __builtin_amdgcn_s_setprio(1);
#pragma unroll
    for (int m = 2; m < 4; ++m)
#pragma unroll
      for (int n = 0; n < 6; ++n) MFMA16(acc[m][n], a0[m], b0[n]);
    __builtin_amdgcn_s_setprio(0);
    SBAR();   // all reads of buf p complete -> safe to overwrite

    // ph3: stage A(t+2), MFMA k1 x m0-1
    if (t + 2 < NT) stageA(p, t + 2);
    __builtin_amdgcn_s_setprio(1);
#pragma unroll
    for (int m = 0; m < 2; ++m)
#pragma unroll
      for (int n = 0; n < 6; ++n) MFMA16(acc[m][n], a1[m], b1[n]);
    __builtin_amdgcn_s_setprio(0);
    SBAR();

    // ph4: stage B(t+2), MFMA k1 x m2-3
    if (t + 2 < NT) stageB(p, t + 2);
    __builtin_amdgcn_s_setprio(1);
#pragma unroll
    for (int m = 2; m < 4; ++m)
#pragma unroll
      for (int n = 0; n < 6; ++n) MFMA16(acc[m][n], a1[m], b1[n]);
    __builtin_amdgcn_s_setprio(0);
  }

#pragma unroll
  for (int m = 0; m < 4; ++m)
#pragma unroll
    for (int n = 0; n < 6; ++n) {
      int c = n0 + wn * 96 + n * 16 + lrow;
      int r0 = m0 + wm * 64 + m * 16 + kq * 4;
      if (c < QD) {
#pragma unroll
        for (int j = 0; j < 4; ++j)
          Qb[(size_t)(r0 + j) * QD + c] = __float2bfloat16(acc[m][n][j]);
      } else if (c < QD + KVD) {
#pragma unroll
        for (int j = 0; j < 4; ++j)
          Kc[(size_t)(r0 + j) * KVD + (c - QD)] = __float2bfloat16(acc[m][n][j]);
      } else {
        union { __hip_bfloat16 b[4]; s4v v; } u;
#pragma unroll
        for (int j = 0; j < 4; ++j) u.b[j] = __float2bfloat16(acc[m][n][j]);
        *(s4v*)&Vt[(size_t)(c - QD - KVD) * SEQ + r0] = u.v;
      }
    }
}

// ---------------- O-projection: R8 4-phase counted-vmcnt 128x256 (verified) ----------------
__global__ __launch_bounds__(512, 2) void k_oproj(const __hip_bfloat16* __restrict__ A,
                                                  const __hip_bfloat16* __restrict__ B,
                                                  float* __restrict__ C) {
  __shared__ __align__(16) __hip_bfloat16 sm[2][128 * 64 + 256 * 64];
  const int t5 = threadIdx.x;
  const int wave = t5 >> 6, lane = t5 & 63;
  const int lrow = lane & 15, kq = lane >> 4;
  const int wm = wave >> 2, wn = wave & 3;
  const int m0 = blockIdx.y * 128, n0 = blockIdx.x * 256;

  auto stageA = [&](int p, int kt) {
#pragma unroll
    for (int it = 0; it < 2; ++it) {
      int chunk = it * 512 + t5;
      int r = chunk >> 3, cc = ((chunk & 7) ^ (r & 7)) * 8;
      gl2lds16(A + (size_t)(m0 + r) * QD + kt * 64 + cc,
               (char*)&sm[p][0] + it * 8192 + wave * 1024);
    }
  };
  auto stageB = [&](int p, int kt) {
#pragma unroll
    for (int it = 0; it < 4; ++it) {
      int chunk = it * 512 + t5;
      int r = chunk >> 3, cc = ((chunk & 7) ^ (r & 7)) * 8;
      gl2lds16(B + (size_t)(n0 + r) * QD + kt * 64 + cc,
               (char*)&sm[p][0] + 16384 + it * 8192 + wave * 1024);
    }
  };

  f4v acc[4][4] = {};

  stageA(0, 0); stageB(0, 0);
  stageA(1, 1); stageB(1, 1);

  const int NT = QD / 64;
#pragma unroll 2
  for (int t = 0; t < NT; ++t) {
    const int p = t & 1;
    const __hip_bfloat16* As = &sm[p][0];
    const __hip_bfloat16* Bs = &sm[p][128 * 64];

    __builtin_amdgcn_sched_barrier(0);
    if (t == NT - 1) asm volatile("s_waitcnt vmcnt(0)" ::: "memory");
    else             asm volatile("s_waitcnt vmcnt(6)" ::: "memory");
    __builtin_amdgcn_s_barrier();
    __builtin_amdgcn_sched_barrier(0);

    // ph1: ds_read k0 (8), MFMA k0 m0-1
    s8v a0[4], b0[4];
#pragma unroll
    for (int m = 0; m < 4; ++m) {
      int row = wm * 64 + m * 16 + lrow;
      a0[m] = *(const s8v*)&As[row * 64 + ((kq * 8) ^ ((row & 7) << 3))];
    }
#pragma unroll
    for (int n = 0; n < 4; ++n) {
      int row = wn * 64 + n * 16 + lrow;
      b0[n] = *(const s8v*)&Bs[row * 64 + ((kq * 8) ^ ((row & 7) << 3))];
    }
    __builtin_amdgcn_s_setprio(1);
#pragma unroll
    for (int m = 0; m < 2; ++m)
#pragma unroll
      for (int n = 0; n < 4; ++n) MFMA16(acc[m][n], a0[m], b0[n]);
    __builtin_amdgcn_s_setprio(0);
    SBAR();

    // ph2: ds_read k1, MFMA k0 m2-3
    s8v a1[4], b1[4];
#pragma unroll
    for (int m = 0; m < 4; ++m) {
      int row = wm * 64 + m * 16 + lrow;
      a1[m] = *(const s8v*)&As[row * 64 + ((32 + kq * 8) ^ ((row & 7) << 3))];
    }
#pragma unroll
    for (int n = 0; n < 4; ++n) {
      int row = wn * 64 + n * 16 + lrow;
      b1[n] = *(const s8v*)&Bs[row * 64 + ((32 + kq * 8) ^ ((row & 7) << 3))];
    }
    __builtin_amdgcn_s_setprio(1);
#pragma unroll
    for (int m = 2; m < 4; ++m)
#pragma unroll
      for (int n = 0; n < 4; ++n) MFMA16(acc[m][n], a0[m], b0[n]);
    __builtin_amdgcn_s_setprio(0);
    SBAR();

    // ph3: stage A(t+2), MFMA k1 m0-1
    if (t + 2 < NT) stageA(p, t + 2);
    __builtin_amdgcn_s_setprio(1);
#pragma unroll
    for (int m = 0; m < 2; ++m)
#pragma unroll
      for (int n = 0; n < 4; ++n) MFMA16(acc[m][n], a1[m], b1[n]);
    __builtin_amdgcn_s_setprio(0);
    SBAR();

    // ph4: stage B(t+2), MFMA k1 m2-3
    if (t + 2 < NT) stageB(p, t + 2);
    __builtin_amdgcn_s_setprio(1);
#pragma unroll
    for (int m = 2; m < 4; ++m)
#pragma unroll
      for (int n = 0; n < 4; ++n) MFMA16(acc[m][n], a1[m], b1[n]);
    __builtin_amdgcn_s_setprio(0);
  }

#pragma unroll
  for (int m = 0; m < 4; ++m)
#pragma unroll
    for (int n = 0; n < 4; ++n)
#pragma unroll
      for (int j = 0; j < 4; ++j) {
        int r = m0 + wm * 64 + m * 16 + kq * 4 + j;
        int c = n0 + wn * 64 + n * 16 + lrow;
        C[(size_t)r * DMODEL + c] = acc[m][n][j];
      }
}

// ---------------- causal flash attention: swapped-QK^T, in-lane l (no ones-column) ----------------
__global__ __launch_bounds__(256, 2) void k_flash(const __hip_bfloat16* __restrict__ Q,
                                                  const __hip_bfloat16* __restrict__ Kb,
                                                  const __hip_bfloat16* __restrict__ Vtg,
                                                  __hip_bfloat16* __restrict__ O) {
  __shared__ __align__(16) __hip_bfloat16 Ks[2][64 * 128];
  __shared__ __align__(16) __hip_bfloat16 Vs[128 * 64];
  __shared__ __align__(16) __hip_bfloat16 Ps[4][16 * 64];
  const int qp = blockIdx.x, h = blockIdx.y, g = h >> 2;
  const int t = threadIdx.x, wave = t >> 6, lane = t & 63;
  const int lrow = lane & 15, kq = lane >> 4;
  const int qtA = qp, qtB = 31 - qp;

  s8v qfA[4], qfB[4];
  {
    const int qrA = qtA * 64 + wave * 16 + lrow;
    const int qrB = qtB * 64 + wave * 16 + lrow;
#pragma unroll
    for (int tt = 0; tt < 4; ++tt) {
      qfA[tt] = *(const s8v*)(Q + (size_t)qrA * QD + h * HDIM + tt * 32 + kq * 8);
      qfB[tt] = *(const s8v*)(Q + (size_t)qrB * QD + h * HDIM + tt * 32 + kq * 8);
    }
  }

  f4v oA[8] = {}, oB[8] = {};
  float mA = -1e30f, mB = -1e30f;     // per-lane running max, q = lrow
  float lA = 0.f, lB = 0.f;           // per-lane running sum, q = lrow

  auto stage_k = [&](int buf, int kv) {
#pragma unroll
    for (int it = 0; it < 4; ++it) {
      int chunk = it * 256 + t;
      int r = chunk >> 4, cc = ((chunk & 15) ^ (r & 7)) * 8;
      gl2lds16(Kb + (size_t)(kv * 64 + r) * KVD + g * HDIM + cc,
               (char*)&Ks[buf][0] + it * 4096 + wave * 1024);
    }
  };
  auto stage_v = [&](int kv) {
#pragma unroll
    for (int it = 0; it < 4; ++it) {
      int chunk = it * 256 + t;
      int d = chunk >> 3, cc = ((chunk & 7) ^ (d & 7)) * 8;
      gl2lds16(Vtg + (size_t)(g * HDIM + d) * SEQ + kv * 64 + cc,
               (char*)Vs + it * 4096 + wave * 1024);
    }
  };

  auto soft_pv = [&](f4v (&s)[4], int qt, int kv, f4v (&acc_o)[8], float& mrun, float& lrun) {
    __hip_bfloat16* P = &Ps[wave][0];
    const bool diag = (kv == qt);
    const int qi = qt * 64 + wave * 16 + lrow;
    const int swz = (lrow & 7) << 3;
    float pv[4][4];
    float mx = -1e30f;
#pragma unroll
    for (int n = 0; n < 4; ++n)
#pragma unroll
      for (int j = 0; j < 4; ++j) {
        float v = s[n][j];
        if (diag) {
          int ki = kv * 64 + n * 16 + kq * 4 + j;
          if (ki > qi) v = -1e30f;
        }
        pv[n][j] = v;
        mx = fmaxf(mx, v);
      }
    mx = fmaxf(mx, __shfl_xor(mx, 16, 64));
    mx = fmaxf(mx, __shfl_xor(mx, 32, 64));
    if (!__all(mx <= mrun)) {        // else fsc==1 exactly for every lane -> elide
      float mnew = fmaxf(mrun, mx);
      float fsc = __expf(mrun - mnew);
      mrun = mnew;
      lrun *= fsc;                   // per-lane q==lrow
      float fj[4];
#pragma unroll
      for (int j = 0; j < 4; ++j) fj[j] = __shfl(fsc, kq * 4 + j, 64);
#pragma unroll
      for (int n = 0; n < 8; ++n) {
        acc_o[n][0] *= fj[0]; acc_o[n][1] *= fj[1];
        acc_o[n][2] *= fj[2]; acc_o[n][3] *= fj[3];
      }
    }
    // P = exp(S - m), bf16-rounded; l sums the SAME bf16-rounded values
    float rsum = 0.f;
    asm volatile("" ::: "memory");
#pragma unroll
    for (int n = 0; n < 4; ++n) {
      union { __hip_bfloat16 b[4]; s4v v; } u;
#pragma unroll
      for (int j = 0; j < 4; ++j) {
        __hip_bfloat16 pb = __float2bfloat16(__expf(pv[n][j] - mrun));
        u.b[j] = pb;
        rsum += __bfloat162float(pb);
      }
      *(s4v*)&P[lrow * 64 + ((n * 16 + kq * 4) ^ swz)] = u.v;
    }
    rsum += __shfl_xor(rsum, 16, 64);
    rsum += __shfl_xor(rsum, 32, 64);
    lrun += rsum;
    asm volatile("" ::: "memory");
#pragma unroll
    for (int tt = 0; tt < 2; ++tt) {
      s8v pa = *(const s8v*)&P[lrow * 64 + ((tt * 32 + kq * 8) ^ swz)];
#pragma unroll
      for (int n = 0; n < 8; ++n) {
        int d = n * 16 + lrow;
        s8v vf = *(const s8v*)&Vs[d * 64 + ((tt * 32 + kq * 8) ^ ((d & 7) << 3))];
        MFMA16(acc_o[n], pa, vf);
      }
    }
  };

  stage_k(0, 0);
  int cur = 0;
  for (int kv = 0; kv <= qtB; ++kv) {
    const bool actA = (kv <= qtA);
    __syncthreads();
    if (kv < qtB) stage_k(cur ^ 1, kv + 1);
    stage_v(kv);

    f4v sB[4] = {}, sA[4] = {};
    if (actA) {
#pragma unroll
      for (int tt = 0; tt < 4; ++tt)
#pragma unroll
        for (int n = 0; n < 4; ++n) {
          int row = n * 16 + lrow;
          s8v kf = *(const s8v*)&Ks[cur][row * 128 + ((tt * 32 + kq * 8) ^ ((row & 7) << 3))];
          MFMA16(sB[n], kf, qfB[tt]);
          MFMA16(sA[n], kf, qfA[tt]);
        }
    } else {
#pragma unroll
      for (int tt = 0; tt < 4; ++tt)
#pragma unroll
        for (int n = 0; n < 4; ++n) {
          int row = n * 16 + lrow;
          s8v kf = *(const s8v*)&Ks[cur][row * 128 + ((tt * 32 + kq * 8) ^ ((row & 7) << 3))];
          MFMA16(sB[n], kf, qfB[tt]);
        }
    }
    __syncthreads();

    soft_pv(sB, qtB, kv, oB, mB, lB);
    if (actA) soft_pv(sA, qtA, kv, oA, mA, lA);
    cur ^= 1;
  }

  float ljB[4], ljA[4];
#pragma unroll
  for (int j = 0; j < 4; ++j) {
    ljB[j] = __shfl(lB, kq * 4 + j, 64);
    ljA[j] = __shfl(lA, kq * 4 + j, 64);
  }
#pragma unroll
  for (int n = 0; n < 8; ++n)
#pragma unroll
    for (int j = 0; j < 4; ++j) {
      int d = n * 16 + lrow;
      int qiB = qtB * 64 + wave * 16 + kq * 4 + j;
      O[(size_t)qiB * QD + h * HDIM + d] = __float2bfloat16(oB[n][j] / ljB[j]);
      int qiA = qtA * 64 + wave * 16 + kq * 4 + j;
      O[(size_t)qiA * QD + h * HDIM + d] = __float2bfloat16(oA[n][j] / ljA[j]);
    }
}

// ---------------- launch ----------------
extern "C" void kernel_launch(void* const* d_in, const int* in_sizes, int n_in,
                              void* d_out, int out_size, void* d_ws, size_t ws_size,
                              hipStream_t stream) {
  const float* x  = (const float*)d_in[0];
  const float* fc = (const float*)d_in[1];
  const float* fs = (const float*)d_in[2];
  const float* wq = (const float*)d_in[3];
  const float* wk = (const float*)d_in[4];
  const float* wv = (const float*)d_in[5];
  const float* wo = (const float*)d_in[6];
  float* out = (float*)d_out;

  char* ws = (char*)d_ws;
  auto alloc = [&](size_t bytes) {
    char* p = ws;
    ws += (bytes + 255) & ~(size_t)255;
    return p;
  };
  __hip_bfloat16* xb  = (__hip_bfloat16*)alloc((size_t)SEQ * DMODEL * 2);
  __hip_bfloat16* wf  = (__hip_bfloat16*)alloc((size_t)QKVN * DMODEL * 2);
  __hip_bfloat16* wob = (__hip_bfloat16*)alloc((size_t)DMODEL * QD * 2);
  __hip_bfloat16* Qb  = (__hip_bfloat16*)alloc((size_t)SEQ * QD * 2);
  __hip_bfloat16* Kc  = (__hip_bfloat16*)alloc((size_t)SEQ * KVD * 2);
  __hip_bfloat16* Vtg = (__hip_bfloat16*)alloc((size_t)KVD * SEQ * 2);
  __hip_bfloat16* Ob  = (__hip_bfloat16*)alloc((size_t)SEQ * QD * 2);

  k_cvt5<<<dim3(24576), dim3(256), 0, stream>>>(x, wq, wk, wv, wo, xb, wf, wob);

  k_qkv<<<dim3(256), dim3(512), 0, stream>>>(xb, wf, Qb, Kc, Vtg);

  k_rope<<<dim3(SEQ * NH * 64 / 256), 256, 0, stream>>>(Qb, fc, fs, NH);
  k_rope<<<dim3(SEQ * NKVH * 64 / 256), 256, 0, stream>>>(Kc, fc, fs, NKVH);

  k_flash<<<dim3(16, NH), 256, 0, stream>>>(Qb, Kc, Vtg, Ob);

  k_oproj<<<dim3(DMODEL / 256, SEQ / 128), dim3(512), 0, stream>>>(Ob, wob, out);
}

// Round 11
// 267.074 us; speedup vs baseline: 1.0524x; 1.0503x over previous
//
#include <hip/hip_runtime.h>
#include <hip/hip_bf16.h>
#include <stdint.h>

#define SEQ    2048
#define DMODEL 4096
#define NH     32
#define NKVH   8
#define HDIM   128
#define KVD    (NKVH*HDIM)   // 1024
#define QD     (NH*HDIM)     // 4096
#define QKVN   (QD + 2*KVD)  // 6144 fused projection columns
#define ASCALE 0.08838834764831845f

typedef __attribute__((ext_vector_type(8))) short s8v;   // 8 bf16
typedef __attribute__((ext_vector_type(4))) short s4v;   // 4 bf16
typedef __attribute__((ext_vector_type(4))) float f4v;   // 4 f32

#define MFMA16(acc, a, b) \
  asm("v_mfma_f32_16x16x32_bf16 %0, %1, %2, %0" : "+v"(acc) : "v"(a), "v"(b))

#define SBAR() do { __builtin_amdgcn_sched_barrier(0); \
                    __builtin_amdgcn_s_barrier();      \
                    __builtin_amdgcn_sched_barrier(0); } while (0)

__device__ __forceinline__ void gl2lds16(const void* g, void* l) {
  __builtin_amdgcn_global_load_lds(
      (const __attribute__((address_space(1))) void*)g,
      (__attribute__((address_space(3))) void*)l, 16, 0, 0);
}

// ---------------- merged f32 -> bf16 convert (5 regions, one launch) ----------------
__global__ __launch_bounds__(256) void k_cvt5(const float* __restrict__ x,
                                              const float* __restrict__ wq,
                                              const float* __restrict__ wk,
                                              const float* __restrict__ wv,
                                              const float* __restrict__ wo,
                                              __hip_bfloat16* __restrict__ xb,
                                              __hip_bfloat16* __restrict__ wf,
                                              __hip_bfloat16* __restrict__ wob) {
  int i = blockIdx.x * 256 + threadIdx.x;
  const float* src;
  __hip_bfloat16* dst;
  float scale = 1.0f;
  if (i < 1048576)       { src = x;  dst = xb; }
  else if (i < 3145728)  { src = wq; dst = wf;  i -= 1048576; scale = ASCALE; }
  else if (i < 3670016)  { src = wk; dst = wf + (size_t)QD * DMODEL;  i -= 3145728; }
  else if (i < 4194304)  { src = wv; dst = wf + (size_t)(QD + KVD) * DMODEL; i -= 3670016; }
  else                   { src = wo; dst = wob; i -= 4194304; }
  const float4* p = (const float4*)src + (size_t)i * 2;
  float4 a = p[0], b = p[1];
  union { __hip_bfloat16 h[8]; s8v v; } o;
  o.h[0] = __float2bfloat16(a.x * scale); o.h[1] = __float2bfloat16(a.y * scale);
  o.h[2] = __float2bfloat16(a.z * scale); o.h[3] = __float2bfloat16(a.w * scale);
  o.h[4] = __float2bfloat16(b.x * scale); o.h[5] = __float2bfloat16(b.y * scale);
  o.h[6] = __float2bfloat16(b.z * scale); o.h[7] = __float2bfloat16(b.w * scale);
  *(s8v*)(dst + (size_t)i * 8) = o.v;
}

// ---------------- fused QKV projection: 4-phase, 4Mx2N waves, fused RoPE epilogue ----------------
// Wave-tile 64x96; per-lane rope partner (c^1) lives in lane^1 -> shfl_xor(1).
// Rope applied to f32 acc BEFORE the single bf16 rounding (fewer roundings than
// the separate rope pass). Region branches are 16-lane-uniform (boundaries at
// 4096/5120 are multiples of 16) -> shfl exec-safe.
__global__ __launch_bounds__(512, 2) void k_qkv(const __hip_bfloat16* __restrict__ A,
                                                const __hip_bfloat16* __restrict__ W,
                                                const float* __restrict__ fc,
                                                const float* __restrict__ fs,
                                                __hip_bfloat16* __restrict__ Qb,
                                                __hip_bfloat16* __restrict__ Kc,
                                                __hip_bfloat16* __restrict__ Vt) {
  __shared__ __align__(16) __hip_bfloat16 sm[2][256 * 64 + 192 * 64];
  const int t5 = threadIdx.x;
  const int wave = t5 >> 6, lane = t5 & 63;
  const int lrow = lane & 15, kq = lane >> 4;
  const int wm = wave >> 1, wn = wave & 1;          // 4M x 2N
  const int mt = blockIdx.x & 7, nt = blockIdx.x >> 3;
  const int m0 = mt * 256, n0 = nt * 192;

  auto stageA = [&](int p, int kt) {
#pragma unroll
    for (int it = 0; it < 4; ++it) {
      int chunk = it * 512 + t5;
      int r = chunk >> 3, cc = ((chunk & 7) ^ (r & 7)) * 8;
      gl2lds16(A + (size_t)(m0 + r) * DMODEL + kt * 64 + cc,
               (char*)&sm[p][0] + it * 8192 + wave * 1024);
    }
  };
  auto stageB = [&](int p, int kt) {
#pragma unroll
    for (int it = 0; it < 3; ++it) {
      int chunk = it * 512 + t5;
      int r = chunk >> 3, cc = ((chunk & 7) ^ (r & 7)) * 8;
      gl2lds16(W + (size_t)(n0 + r) * DMODEL + kt * 64 + cc,
               (char*)&sm[p][0] + 32768 + it * 8192 + wave * 1024);
    }
  };

  f4v acc[4][6] = {};

  stageA(0, 0); stageB(0, 0);
  stageA(1, 1); stageB(1, 1);

  const int NT = DMODEL / 64;
#pragma unroll 2
  for (int t = 0; t < NT; ++t) {
    const int p = t & 1;
    const __hip_bfloat16* As = &sm[p][0];
    const __hip_bfloat16* Bs = &sm[p][256 * 64];

    __builtin_amdgcn_sched_barrier(0);
    if (t == NT - 1) asm volatile("s_waitcnt vmcnt(0)" ::: "memory");
    else             asm volatile("s_waitcnt vmcnt(7)" ::: "memory");
    __builtin_amdgcn_s_barrier();
    __builtin_amdgcn_sched_barrier(0);

    // ph1: read k0 frags (10), MFMA k0 x m0-1 (12)
    s8v a0[4], b0[6];
#pragma unroll
    for (int m = 0; m < 4; ++m) {
      int row = wm * 64 + m * 16 + lrow;
      a0[m] = *(const s8v*)&As[row * 64 + ((kq * 8) ^ ((row & 7) << 3))];
    }
#pragma unroll
    for (int n = 0; n < 6; ++n) {
      int row = wn * 96 + n * 16 + lrow;
      b0[n] = *(const s8v*)&Bs[row * 64 + ((kq * 8) ^ ((row & 7) << 3))];
    }
    __builtin_amdgcn_s_setprio(1);
#pragma unroll
    for (int m = 0; m < 2; ++m)
#pragma unroll
      for (int n = 0; n < 6; ++n) MFMA16(acc[m][n], a0[m], b0[n]);
    __builtin_amdgcn_s_setprio(0);
    SBAR();

    // ph2: read k1 frags (10), MFMA k0 x m2-3 (12)
    s8v a1[4], b1[6];
#pragma unroll
    for (int m = 0; m < 4; ++m) {
      int row = wm * 64 + m * 16 + lrow;
      a1[m] = *(const s8v*)&As[row * 64 + ((32 + kq * 8) ^ ((row & 7) << 3))];
    }
#pragma unroll
    for (int n = 0; n < 6; ++n) {
      int row = wn * 96 + n * 16 + lrow;
      b1[n] = *(const s8v*)&Bs[row * 64 + ((32 + kq * 8) ^ ((row & 7) << 3))];
    }
    __builtin_amdgcn_s_setprio(1);
#pragma unroll
    for (int m = 2; m < 4; ++m)
#pragma unroll
      for (int n = 0; n < 6; ++n) MFMA16(acc[m][n], a0[m], b0[n]);
    __builtin_amdgcn_s_setprio(0);
    SBAR();   // all reads of buf p complete -> safe to overwrite

    // ph3: stage A(t+2), MFMA k1 x m0-1
    if (t + 2 < NT) stageA(p, t + 2);
    __builtin_amdgcn_s_setprio(1);
#pragma unroll
    for (int m = 0; m < 2; ++m)
#pragma unroll
      for (int n = 0; n < 6; ++n) MFMA16(acc[m][n], a1[m], b1[n]);
    __builtin_amdgcn_s_setprio(0);
    SBAR();

    // ph4: stage B(t+2), MFMA k1 x m2-3
    if (t + 2 < NT) stageB(p, t + 2);
    __builtin_amdgcn_s_setprio(1);
#pragma unroll
    for (int m = 2; m < 4; ++m)
#pragma unroll
      for (int n = 0; n < 6; ++n) MFMA16(acc[m][n], a1[m], b1[n]);
    __builtin_amdgcn_s_setprio(0);
  }

  // epilogue: Q/K get fused rope; V written transposed
#pragma unroll
  for (int m = 0; m < 4; ++m)
#pragma unroll
    for (int n = 0; n < 6; ++n) {
      int c = n0 + wn * 96 + n * 16 + lrow;
      int r0 = m0 + wm * 64 + m * 16 + kq * 4;
      if (c < QD + KVD) {
        const int ii = (c & 127) >> 1;       // rope angle index (same for pair)
        const bool odd = c & 1;
        float vout[4];
#pragma unroll
        for (int j = 0; j < 4; ++j) {
          float v = acc[m][n][j];
          float pvt = __shfl_xor(v, 1, 64);  // partner (c^1), lane^1
          float cv = fc[(size_t)(r0 + j) * 64 + ii];
          float sv = fs[(size_t)(r0 + j) * 64 + ii];
          // even c: v=tr, pvt=ti -> tr*cos - ti*sin ; odd c: v=ti, pvt=tr -> tr*sin + ti*cos
          vout[j] = odd ? (pvt * sv + v * cv) : (v * cv - pvt * sv);
        }
        if (c < QD) {
#pragma unroll
          for (int j = 0; j < 4; ++j)
            Qb[(size_t)(r0 + j) * QD + c] = __float2bfloat16(vout[j]);
        } else {
#pragma unroll
          for (int j = 0; j < 4; ++j)
            Kc[(size_t)(r0 + j) * KVD + (c - QD)] = __float2bfloat16(vout[j]);
        }
      } else {
        union { __hip_bfloat16 b[4]; s4v v; } u;
#pragma unroll
        for (int j = 0; j < 4; ++j) u.b[j] = __float2bfloat16(acc[m][n][j]);
        *(s4v*)&Vt[(size_t)(c - QD - KVD) * SEQ + r0] = u.v;
      }
    }
}

// ---------------- O-projection: 4-phase counted-vmcnt 128x256 (R8/R10, verified) ----------------
__global__ __launch_bounds__(512, 2) void k_oproj(const __hip_bfloat16* __restrict__ A,
                                                  const __hip_bfloat16* __restrict__ B,
                                                  float* __restrict__ C) {
  __shared__ __align__(16) __hip_bfloat16 sm[2][128 * 64 + 256 * 64];
  const int t5 = threadIdx.x;
  const int wave = t5 >> 6, lane = t5 & 63;
  const int lrow = lane & 15, kq = lane >> 4;
  const int wm = wave >> 2, wn = wave & 3;
  const int m0 = blockIdx.y * 128, n0 = blockIdx.x * 256;

  auto stageA = [&](int p, int kt) {
#pragma unroll
    for (int it = 0; it < 2; ++it) {
      int chunk = it * 512 + t5;
      int r = chunk >> 3, cc = ((chunk & 7) ^ (r & 7)) * 8;
      gl2lds16(A + (size_t)(m0 + r) * QD + kt * 64 + cc,
               (char*)&sm[p][0] + it * 8192 + wave * 1024);
    }
  };
  auto stageB = [&](int p, int kt) {
#pragma unroll
    for (int it = 0; it < 4; ++it) {
      int chunk = it * 512 + t5;
      int r = chunk >> 3, cc = ((chunk & 7) ^ (r & 7)) * 8;
      gl2lds16(B + (size_t)(n0 + r) * QD + kt * 64 + cc,
               (char*)&sm[p][0] + 16384 + it * 8192 + wave * 1024);
    }
  };

  f4v acc[4][4] = {};

  stageA(0, 0); stageB(0, 0);
  stageA(1, 1); stageB(1, 1);

  const int NT = QD / 64;
#pragma unroll 2
  for (int t = 0; t < NT; ++t) {
    const int p = t & 1;
    const __hip_bfloat16* As = &sm[p][0];
    const __hip_bfloat16* Bs = &sm[p][128 * 64];

    __builtin_amdgcn_sched_barrier(0);
    if (t == NT - 1) asm volatile("s_waitcnt vmcnt(0)" ::: "memory");
    else             asm volatile("s_waitcnt vmcnt(6)" ::: "memory");
    __builtin_amdgcn_s_barrier();
    __builtin_amdgcn_sched_barrier(0);

    s8v a0[4], b0[4];
#pragma unroll
    for (int m = 0; m < 4; ++m) {
      int row = wm * 64 + m * 16 + lrow;
      a0[m] = *(const s8v*)&As[row * 64 + ((kq * 8) ^ ((row & 7) << 3))];
    }
#pragma unroll
    for (int n = 0; n < 4; ++n) {
      int row = wn * 64 + n * 16 + lrow;
      b0[n] = *(const s8v*)&Bs[row * 64 + ((kq * 8) ^ ((row & 7) << 3))];
    }
    __builtin_amdgcn_s_setprio(1);
#pragma unroll
    for (int m = 0; m < 2; ++m)
#pragma unroll
      for (int n = 0; n < 4; ++n) MFMA16(acc[m][n], a0[m], b0[n]);
    __builtin_amdgcn_s_setprio(0);
    SBAR();

    s8v a1[4], b1[4];
#pragma unroll
    for (int m = 0; m < 4; ++m) {
      int row = wm * 64 + m * 16 + lrow;
      a1[m] = *(const s8v*)&As[row * 64 + ((32 + kq * 8) ^ ((row & 7) << 3))];
    }
#pragma unroll
    for (int n = 0; n < 4; ++n) {
      int row = wn * 64 + n * 16 + lrow;
      b1[n] = *(const s8v*)&Bs[row * 64 + ((32 + kq * 8) ^ ((row & 7) << 3))];
    }
    __builtin_amdgcn_s_setprio(1);
#pragma unroll
    for (int m = 2; m < 4; ++m)
#pragma unroll
      for (int n = 0; n < 4; ++n) MFMA16(acc[m][n], a0[m], b0[n]);
    __builtin_amdgcn_s_setprio(0);
    SBAR();

    if (t + 2 < NT) stageA(p, t + 2);
    __builtin_amdgcn_s_setprio(1);
#pragma unroll
    for (int m = 0; m < 2; ++m)
#pragma unroll
      for (int n = 0; n < 4; ++n) MFMA16(acc[m][n], a1[m], b1[n]);
    __builtin_amdgcn_s_setprio(0);
    SBAR();

    if (t + 2 < NT) stageB(p, t + 2);
    __builtin_amdgcn_s_setprio(1);
#pragma unroll
    for (int m = 2; m < 4; ++m)
#pragma unroll
      for (int n = 0; n < 4; ++n) MFMA16(acc[m][n], a1[m], b1[n]);
    __builtin_amdgcn_s_setprio(0);
  }

#pragma unroll
  for (int m = 0; m < 4; ++m)
#pragma unroll
    for (int n = 0; n < 4; ++n)
#pragma unroll
      for (int j = 0; j < 4; ++j) {
        int r = m0 + wm * 64 + m * 16 + kq * 4 + j;
        int c = n0 + wn * 64 + n * 16 + lrow;
        C[(size_t)r * DMODEL + c] = acc[m][n][j];
      }
}

// ---------------- causal flash attention: swapped-QK^T + ones-column l (R8, verified) ----------------
__global__ __launch_bounds__(256, 2) void k_flash(const __hip_bfloat16* __restrict__ Q,
                                                  const __hip_bfloat16* __restrict__ Kb,
                                                  const __hip_bfloat16* __restrict__ Vtg,
                                                  __hip_bfloat16* __restrict__ O) {
  __shared__ __align__(16) __hip_bfloat16 Ks[2][64 * 128];
  __shared__ __align__(16) __hip_bfloat16 Vs[144 * 64];   // rows 128..143 = ones
  __shared__ __align__(16) __hip_bfloat16 Ps[4][16 * 64];
  const int qp = blockIdx.x, h = blockIdx.y, g = h >> 2;
  const int t = threadIdx.x, wave = t >> 6, lane = t & 63;
  const int lrow = lane & 15, kq = lane >> 4;
  const int qtA = qp, qtB = 31 - qp;

  s8v qfA[4], qfB[4];
  {
    const int qrA = qtA * 64 + wave * 16 + lrow;
    const int qrB = qtB * 64 + wave * 16 + lrow;
#pragma unroll
    for (int tt = 0; tt < 4; ++tt) {
      qfA[tt] = *(const s8v*)(Q + (size_t)qrA * QD + h * HDIM + tt * 32 + kq * 8);
      qfB[tt] = *(const s8v*)(Q + (size_t)qrB * QD + h * HDIM + tt * 32 + kq * 8);
    }
  }

  if (t < 128) {
    union { __hip_bfloat16 h8[8]; s8v v; } one;
#pragma unroll
    for (int e = 0; e < 8; ++e) one.h8[e] = __float2bfloat16(1.0f);
    *(s8v*)&Vs[128 * 64 + t * 8] = one.v;
  }

  f4v oA[9] = {}, oB[9] = {};   // [8] = l accumulator (ones-column)
  float mA = -1e30f, mB = -1e30f;

  auto stage_k = [&](int buf, int kv) {
#pragma unroll
    for (int it = 0; it < 4; ++it) {
      int chunk = it * 256 + t;
      int r = chunk >> 4, cc = ((chunk & 15) ^ (r & 7)) * 8;
      gl2lds16(Kb + (size_t)(kv * 64 + r) * KVD + g * HDIM + cc,
               (char*)&Ks[buf][0] + it * 4096 + wave * 1024);
    }
  };
  auto stage_v = [&](int kv) {
#pragma unroll
    for (int it = 0; it < 4; ++it) {
      int chunk = it * 256 + t;
      int d = chunk >> 3, cc = ((chunk & 7) ^ (d & 7)) * 8;
      gl2lds16(Vtg + (size_t)(g * HDIM + d) * SEQ + kv * 64 + cc,
               (char*)Vs + it * 4096 + wave * 1024);
    }
  };

  auto soft_pv = [&](f4v (&s)[4], int qt, int kv, f4v (&acc_o)[9], float& mrun) {
    __hip_bfloat16* P = &Ps[wave][0];
    const bool diag = (kv == qt);
    const int qi = qt * 64 + wave * 16 + lrow;
    const int swz = (lrow & 7) << 3;
    float pv[4][4];
    float mx = -1e30f;
#pragma unroll
    for (int n = 0; n < 4; ++n)
#pragma unroll
      for (int j = 0; j < 4; ++j) {
        float v = s[n][j];
        if (diag) {
          int ki = kv * 64 + n * 16 + kq * 4 + j;
          if (ki > qi) v = -1e30f;
        }
        pv[n][j] = v;
        mx = fmaxf(mx, v);
      }
    mx = fmaxf(mx, __shfl_xor(mx, 16, 64));
    mx = fmaxf(mx, __shfl_xor(mx, 32, 64));
    if (!__all(mx <= mrun)) {
      float mnew = fmaxf(mrun, mx);
      float fsc = __expf(mrun - mnew);
      mrun = mnew;
      float fj[4];
#pragma unroll
      for (int j = 0; j < 4; ++j) fj[j] = __shfl(fsc, kq * 4 + j, 64);
#pragma unroll
      for (int n = 0; n < 9; ++n) {
        acc_o[n][0] *= fj[0]; acc_o[n][1] *= fj[1];
        acc_o[n][2] *= fj[2]; acc_o[n][3] *= fj[3];
      }
    }
    asm volatile("" ::: "memory");
#pragma unroll
    for (int n = 0; n < 4; ++n) {
      union { __hip_bfloat16 b[4]; s4v v; } u;
#pragma unroll
      for (int j = 0; j < 4; ++j) u.b[j] = __float2bfloat16(__expf(pv[n][j] - mrun));
      *(s4v*)&P[lrow * 64 + ((n * 16 + kq * 4) ^ swz)] = u.v;
    }
    asm volatile("" ::: "memory");
#pragma unroll
    for (int tt = 0; tt < 2; ++tt) {
      s8v pa = *(const s8v*)&P[lrow * 64 + ((tt * 32 + kq * 8) ^ swz)];
#pragma unroll
      for (int n = 0; n < 9; ++n) {          // n==8: ones rows -> l accumulation
        int d = n * 16 + lrow;
        s8v vf = *(const s8v*)&Vs[d * 64 + ((tt * 32 + kq * 8) ^ ((d & 7) << 3))];
        MFMA16(acc_o[n], pa, vf);
      }
    }
  };

  stage_k(0, 0);
  int cur = 0;
  for (int kv = 0; kv <= qtB; ++kv) {
    const bool actA = (kv <= qtA);
    __syncthreads();
    if (kv < qtB) stage_k(cur ^ 1, kv + 1);
    stage_v(kv);

    f4v sB[4] = {}, sA[4] = {};
    if (actA) {
#pragma unroll
      for (int tt = 0; tt < 4; ++tt)
#pragma unroll
        for (int n = 0; n < 4; ++n) {
          int row = n * 16 + lrow;
          s8v kf = *(const s8v*)&Ks[cur][row * 128 + ((tt * 32 + kq * 8) ^ ((row & 7) << 3))];
          MFMA16(sB[n], kf, qfB[tt]);
          MFMA16(sA[n], kf, qfA[tt]);
        }
    } else {
#pragma unroll
      for (int tt = 0; tt < 4; ++tt)
#pragma unroll
        for (int n = 0; n < 4; ++n) {
          int row = n * 16 + lrow;
          s8v kf = *(const s8v*)&Ks[cur][row * 128 + ((tt * 32 + kq * 8) ^ ((row & 7) << 3))];
          MFMA16(sB[n], kf, qfB[tt]);
        }
    }
    __syncthreads();

    soft_pv(sB, qtB, kv, oB, mB);
    if (actA) soft_pv(sA, qtA, kv, oA, mA);
    cur ^= 1;
  }

#pragma unroll
  for (int n = 0; n < 8; ++n)
#pragma unroll
    for (int j = 0; j < 4; ++j) {
      int d = n * 16 + lrow;
      int qiB = qtB * 64 + wave * 16 + kq * 4 + j;
      O[(size_t)qiB * QD + h * HDIM + d] = __float2bfloat16(oB[n][j] / oB[8][j]);
      int qiA = qtA * 64 + wave * 16 + kq * 4 + j;
      O[(size_t)qiA * QD + h * HDIM + d] = __float2bfloat16(oA[n][j] / oA[8][j]);
    }
}

// ---------------- launch ----------------
extern "C" void kernel_launch(void* const* d_in, const int* in_sizes, int n_in,
                              void* d_out, int out_size, void* d_ws, size_t ws_size,
                              hipStream_t stream) {
  const float* x  = (const float*)d_in[0];
  const float* fc = (const float*)d_in[1];
  const float* fs = (const float*)d_in[2];
  const float* wq = (const float*)d_in[3];
  const float* wk = (const float*)d_in[4];
  const float* wv = (const float*)d_in[5];
  const float* wo = (const float*)d_in[6];
  float* out = (float*)d_out;

  char* ws = (char*)d_ws;
  auto alloc = [&](size_t bytes) {
    char* p = ws;
    ws += (bytes + 255) & ~(size_t)255;
    return p;
  };
  __hip_bfloat16* xb  = (__hip_bfloat16*)alloc((size_t)SEQ * DMODEL * 2);
  __hip_bfloat16* wf  = (__hip_bfloat16*)alloc((size_t)QKVN * DMODEL * 2);
  __hip_bfloat16* wob = (__hip_bfloat16*)alloc((size_t)DMODEL * QD * 2);
  __hip_bfloat16* Qb  = (__hip_bfloat16*)alloc((size_t)SEQ * QD * 2);
  __hip_bfloat16* Kc  = (__hip_bfloat16*)alloc((size_t)SEQ * KVD * 2);
  __hip_bfloat16* Vtg = (__hip_bfloat16*)alloc((size_t)KVD * SEQ * 2);
  __hip_bfloat16* Ob  = (__hip_bfloat16*)alloc((size_t)SEQ * QD * 2);

  k_cvt5<<<dim3(24576), dim3(256), 0, stream>>>(x, wq, wk, wv, wo, xb, wf, wob);

  k_qkv<<<dim3(256), dim3(512), 0, stream>>>(xb, wf, fc, fs, Qb, Kc, Vtg);

  k_flash<<<dim3(16, NH), 256, 0, stream>>>(Qb, Kc, Vtg, Ob);

  k_oproj<<<dim3(DMODEL / 256, SEQ / 128), dim3(512), 0, stream>>>(Ob, wob, out);
}